// Round 10
// baseline (461.007 us; speedup 1.0000x reference)
//
#include <hip/hip_runtime.h>
#include <hip/hip_bf16.h>
#include <math.h>

#define T_LEN 2048
#define RC 256
#define DIM 1024
#define VOCAB 50257
#define NT 32              // K tiles: 1024 / 32
#define SLOT 8192          // ushorts per LDS tile slot: 256 rows x 32 cols

using short8  = __attribute__((ext_vector_type(8))) short;
using f32x4   = __attribute__((ext_vector_type(4))) float;

#define VMCNT(n) asm volatile("s_waitcnt vmcnt(" #n ")" ::: "memory")
#define LGKM(n)  asm volatile("s_waitcnt lgkmcnt(" #n ")" ::: "memory")
#define SCHED_FENCE() __builtin_amdgcn_sched_barrier(0)

__device__ __forceinline__ unsigned short f2bf(float f) {
    unsigned int u = __float_as_uint(f);
    u += 0x7fffu + ((u >> 16) & 1u);          // round-to-nearest-even
    return (unsigned short)(u >> 16);
}

// HW packed cvt: dst = {lo16=bf16(a), hi16=bf16(b)}, RNE
__device__ __forceinline__ unsigned int cvt_pk_bf16(float a, float b) {
    unsigned int r;
    asm volatile("v_cvt_pk_bf16_f32 %0, %1, %2" : "=v"(r) : "v"(a), "v"(b));
    return r;
}

__device__ __forceinline__ void async_load16(void* lds, const void* g) {
    __builtin_amdgcn_global_load_lds(
        (const __attribute__((address_space(1))) void*)g,
        (__attribute__((address_space(3))) void*)lds,
        16, 0, 0);
}

// ---------------- K1: MU = gather(token_to_mu_w^T, ids) + pos ----------------
__global__ __launch_bounds__(256) void mu_kernel(
    const int* __restrict__ ids, const float* __restrict__ tokw,
    const float* __restrict__ pos, float* __restrict__ mu) {
    int t = blockIdx.x, k = threadIdx.x;
    int id = ids[t];
    float v = tokw[(size_t)k * VOCAB + id] + pos[t * RC + k];
    mu[t * RC + k] = v;
}

// ---------------- K2: h_pre = gelu(MU @ w1^T + b1) ----------------
__global__ __launch_bounds__(256) void gemm1_gelu_kernel(
    const float* __restrict__ mu, const float* __restrict__ w1,
    const float* __restrict__ b1, float* __restrict__ hpre) {
    __shared__ float xs[16][RC];
    const int tg = blockIdx.x, ng = blockIdx.y, tid = threadIdx.x;
    const int t0 = tg * 16;
    {
        const float4* src = (const float4*)(mu + (size_t)t0 * RC);
        float4* dst = (float4*)&xs[0][0];
        #pragma unroll
        for (int i = 0; i < 4; ++i) dst[tid + 256 * i] = src[tid + 256 * i];
    }
    __syncthreads();
    const int d = ng * 256 + tid;
    float acc[16];
    const float bias = b1[d];
    #pragma unroll
    for (int t = 0; t < 16; ++t) acc[t] = bias;
    const float4* w1r = (const float4*)(w1 + (size_t)d * RC);
    for (int k4 = 0; k4 < RC / 4; ++k4) {
        const float4 w = w1r[k4];
        #pragma unroll
        for (int t = 0; t < 16; ++t) {
            const float4 xv = *(const float4*)&xs[t][k4 * 4];
            acc[t] += w.x * xv.x + w.y * xv.y + w.z * xv.z + w.w * xv.w;
        }
    }
    #pragma unroll
    for (int t = 0; t < 16; ++t) {
        float x = acc[t];
        float g = 0.5f * x * (1.0f + erff(x * 0.70710678118654752f));
        hpre[(size_t)(t0 + t) * DIM + d] = g;
    }
}

// ---------------- K3: LayerNorm -> bf16 h ----------------
__global__ __launch_bounds__(256) void ln_kernel(
    const float* __restrict__ hpre, const float* __restrict__ lnw,
    const float* __restrict__ lnb, unsigned short* __restrict__ h) {
    const int t = blockIdx.x, tid = threadIdx.x;
    const float4 v = ((const float4*)(hpre + (size_t)t * DIM))[tid];
    float s  = v.x + v.y + v.z + v.w;
    float ss = v.x * v.x + v.y * v.y + v.z * v.z + v.w * v.w;
    #pragma unroll
    for (int off = 32; off > 0; off >>= 1) {
        s  += __shfl_down(s, off, 64);
        ss += __shfl_down(ss, off, 64);
    }
    __shared__ float red[8];
    const int wid = tid >> 6, lane = tid & 63;
    if (lane == 0) { red[wid] = s; red[4 + wid] = ss; }
    __syncthreads();
    const float S  = red[0] + red[1] + red[2] + red[3];
    const float SS = red[4] + red[5] + red[6] + red[7];
    const float mean = S * (1.0f / DIM);
    const float var  = SS * (1.0f / DIM) - mean * mean;
    const float inv  = 1.0f / sqrtf(var + 1e-6f);
    const float4 wv = ((const float4*)lnw)[tid];
    const float4 bv = ((const float4*)lnb)[tid];
    ushort4 o;
    o.x = f2bf((v.x - mean) * inv * wv.x + bv.x);
    o.y = f2bf((v.y - mean) * inv * wv.y + bv.y);
    o.z = f2bf((v.z - mean) * inv * wv.z + bv.z);
    o.w = f2bf((v.w - mean) * inv * wv.w + bv.w);
    ((ushort4*)h)[(size_t)t * (DIM / 4) + tid] = o;
}

// ---------------- K4: w2 f32 -> bf16 (HW packed cvt) ----------------
__global__ __launch_bounds__(256) void cvt_kernel(
    const float* __restrict__ src, unsigned int* __restrict__ dst, int n8) {
    int i = blockIdx.x * 256 + threadIdx.x;
    const int stride = gridDim.x * 256;
    for (; i < n8; i += stride) {
        const float4 a = ((const float4*)src)[2 * i];
        const float4 b = ((const float4*)src)[2 * i + 1];
        uint4 o;
        o.x = cvt_pk_bf16(a.x, a.y);
        o.y = cvt_pk_bf16(a.z, a.w);
        o.z = cvt_pk_bf16(b.x, b.y);
        o.w = cvt_pk_bf16(b.z, b.w);
        ((uint4*)dst)[i] = o;
    }
}

// ---------------- K5: logits = h @ w2^T + b2 ----------------
// 256x256 block, 512 threads, 8 waves (2M x 4N), wave tile 128x64.
// BK=32, ring-4 LDS (128 KiB), stage distance 3, derived vmcnt(6),
// SOFTWARE-PIPELINED register loads: frags for phase p+1 issue under
// phase p's MFMA, counted lgkmcnt.  2 barriers/tile.  T1/T2/T5.
__device__ __forceinline__ void stage_A512(
    const unsigned short* __restrict__ A, unsigned short* dst,
    int m0, int kt, int tid, int gsrc) {
    #pragma unroll
    for (int p = 0; p < 2; ++p) {
        const int idx = p * 512 + tid;
        const int row = idx >> 2;
        async_load16(dst + (size_t)idx * 8,
                     A + (size_t)(m0 + row) * DIM + kt * 32 + gsrc * 8);
    }
}
__device__ __forceinline__ void stage_B512(
    const unsigned short* __restrict__ B, unsigned short* dst,
    int n0, int kt, int tid, int gsrc) {
    #pragma unroll
    for (int p = 0; p < 2; ++p) {
        const int idx = p * 512 + tid;
        int row = n0 + (idx >> 2); if (row > VOCAB - 1) row = VOCAB - 1;
        async_load16(dst + (size_t)idx * 8,
                     B + (size_t)row * DIM + kt * 32 + gsrc * 8);
    }
}

// One K-tile: 2 phases.  BF_USE = bf regs holding tile t's B frags;
// BF_LOAD receives tile t+1's B frags (issued under mh=1 MFMA).
#define TILE_BODY(T, BF_USE, BF_LOAD)                                          \
  {                                                                            \
    const int t_  = (T);                                                       \
    const int cur = t_ & 3;                                                    \
    const int nxt = (t_ + 1) & 3;                                              \
    const int st  = (t_ + 3) & 3;                                              \
    const unsigned short* As_t = As + cur * SLOT;                              \
    /* ---- phase even (mh=0): MFMA on af_e x BF_USE ---- */                   \
    _Pragma("unroll")                                                          \
    for (int m = 0; m < 4; ++m)                                                \
        af_o[m] = *(const short8*)(As_t + (arow0 + (m + 4) * 16) * 32 + xr);   \
    if (t_ + 3 < NT)                                                           \
        stage_A512(A, As + st * SLOT, m0, t_ + 3, tid, gsrc);                  \
    SCHED_FENCE();                                                             \
    LGKM(4);              /* af_e + BF_USE landed; af_o may fly */             \
    SCHED_FENCE();                                                             \
    __builtin_amdgcn_s_setprio(1);                                             \
    _Pragma("unroll")                                                          \
    for (int m = 0; m < 4; ++m)                                                \
        _Pragma("unroll")                                                      \
        for (int n = 0; n < 4; ++n)                                            \
            acc[m][n] = __builtin_amdgcn_mfma_f32_16x16x32_bf16(               \
                af_e[m], BF_USE[n], acc[m][n], 0, 0, 0);                       \
    __builtin_amdgcn_s_setprio(0);                                             \
    SCHED_FENCE();                                                             \
    if (t_ + 3 < NT) { VMCNT(6); } else { VMCNT(0); }                          \
    __builtin_amdgcn_s_barrier();   /* tile t+1 LDS ready for all waves */     \
    /* ---- phase odd (mh=1): MFMA on af_o x BF_USE ---- */                    \
    if (t_ + 1 < NT) {                                                         \
        const unsigned short* As_n = As + nxt * SLOT;                          \
        const unsigned short* Bs_n = Bs + nxt * SLOT;                          \
        _Pragma("unroll")                                                      \
        for (int m = 0; m < 4; ++m)                                            \
            af_e[m] = *(const short8*)(As_n + (arow0 + m * 16) * 32 + xr);     \
        _Pragma("unroll")                                                      \
        for (int n = 0; n < 4; ++n)                                            \
            BF_LOAD[n] = *(const short8*)(Bs_n + (brow0 + n * 16) * 32 + xr);  \
    }                                                                          \
    if (t_ + 3 < NT)                                                           \
        stage_B512(B, Bs + st * SLOT, n0, t_ + 3, tid, gsrc);                  \
    SCHED_FENCE();                                                             \
    if (t_ + 1 < NT) { LGKM(8); } else { LGKM(0); }  /* af_o landed */         \
    SCHED_FENCE();                                                             \
    __builtin_amdgcn_s_setprio(1);                                             \
    _Pragma("unroll")                                                          \
    for (int m = 0; m < 4; ++m)                                                \
        _Pragma("unroll")                                                      \
        for (int n = 0; n < 4; ++n)                                            \
            acc[m + 4][n] = __builtin_amdgcn_mfma_f32_16x16x32_bf16(           \
                af_o[m], BF_USE[n], acc[m + 4][n], 0, 0, 0);                   \
    __builtin_amdgcn_s_setprio(0);                                             \
    SCHED_FENCE();                                                             \
    __builtin_amdgcn_s_barrier();   /* orders reads-done before next stage */  \
  }

__global__ __launch_bounds__(512, 2) void gemm2_kernel(
    const unsigned short* __restrict__ A, const unsigned short* __restrict__ B,
    const float* __restrict__ b2, float* __restrict__ out) {
    __shared__ unsigned short As[4 * SLOT];   // 64 KiB
    __shared__ unsigned short Bs[4 * SLOT];   // 64 KiB

    const int tid  = threadIdx.x;
    // T1: bijective XCD swizzle (gridDim.x = 1576 = 8*197), M-fastest
    const int cpx  = gridDim.x >> 3;   // 197
    const int wgid = (blockIdx.x & 7) * cpx + (blockIdx.x >> 3);
    const int m0   = (wgid & 7) << 8;
    const int n0   = (wgid >> 3) << 8;

    const int lane = tid & 63;
    const int lr   = lane & 15;
    const int lk   = lane >> 4;
    const int wid  = tid >> 6;
    const int wr   = wid >> 2;          // 0..1  (M)
    const int wc   = wid & 3;           // 0..3  (N)
    // T2 read-side swizzle (conflict-free, verified R2-R9)
    const int xr   = (lk ^ ((lr >> 1) & 3)) * 8;   // ushort offset within row
    const int arow0 = wr * 128 + lr;
    const int brow0 = wc * 64 + lr;
    // T2 source-side granule for linear global_load_lds dest
    const int gsrc = (tid & 3) ^ ((tid >> 3) & 3);

    f32x4 acc[8][4];
    #pragma unroll
    for (int m = 0; m < 8; ++m)
        #pragma unroll
        for (int n = 0; n < 4; ++n) acc[m][n] = {0.f, 0.f, 0.f, 0.f};

    // prologue: stage tiles 0,1,2 (issue order fenced -> vmcnt exact)
    stage_A512(A, As, m0, 0, tid, gsrc);
    stage_B512(B, Bs, n0, 0, tid, gsrc);
    SCHED_FENCE();
    stage_A512(A, As + SLOT, m0, 1, tid, gsrc);
    stage_B512(B, Bs + SLOT, n0, 1, tid, gsrc);
    SCHED_FENCE();
    stage_A512(A, As + 2 * SLOT, m0, 2, tid, gsrc);
    stage_B512(B, Bs + 2 * SLOT, n0, 2, tid, gsrc);
    SCHED_FENCE();
    VMCNT(8);                       // tile 0 landed; tiles 1,2 in flight
    __builtin_amdgcn_s_barrier();

    // preload tile-0 frags: af_e (mh=0) + bfA
    short8 af_e[4], af_o[4], bfA[4], bfB[4];
    #pragma unroll
    for (int m = 0; m < 4; ++m)
        af_e[m] = *(const short8*)(As + (arow0 + m * 16) * 32 + xr);
    #pragma unroll
    for (int n = 0; n < 4; ++n)
        bfA[n] = *(const short8*)(Bs + (brow0 + n * 16) * 32 + xr);

    #pragma unroll 1
    for (int tt = 0; tt < NT; tt += 2) {
        TILE_BODY(tt,     bfA, bfB);   // uses bfA(tile tt),   loads bfB(tile tt+1)
        TILE_BODY(tt + 1, bfB, bfA);   // uses bfB(tile tt+1), loads bfA(tile tt+2)
    }

    // epilogue: C row = frag_row + (lane>>4)*4 + j, col = lane&15
    float bias[4]; int col[4]; bool ok[4];
    #pragma unroll
    for (int n = 0; n < 4; ++n) {
        col[n] = n0 + wc * 64 + n * 16 + lr;
        ok[n]  = col[n] < VOCAB;
        bias[n] = ok[n] ? b2[col[n]] : 0.f;
    }
    #pragma unroll
    for (int m = 0; m < 8; ++m) {
        const int row = m0 + wr * 128 + m * 16 + lk * 4;
        #pragma unroll
        for (int n = 0; n < 4; ++n) {
            if (ok[n]) {
                #pragma unroll
                for (int j = 0; j < 4; ++j)
                    out[(size_t)(row + j) * VOCAB + col[n]] = acc[m][n][j] + bias[n];
            }
        }
    }
}

extern "C" void kernel_launch(void* const* d_in, const int* in_sizes, int n_in,
                              void* d_out, int out_size, void* d_ws, size_t ws_size,
                              hipStream_t stream) {
    (void)in_sizes; (void)n_in; (void)out_size; (void)ws_size;
    const int*   ids  = (const int*)d_in[0];
    const float* tokw = (const float*)d_in[1];
    const float* pos  = (const float*)d_in[2];
    const float* w1   = (const float*)d_in[3];
    const float* b1   = (const float*)d_in[4];
    const float* lnw  = (const float*)d_in[5];
    const float* lnb  = (const float*)d_in[6];
    const float* w2   = (const float*)d_in[7];
    const float* b2   = (const float*)d_in[8];

    float* logits = (float*)d_out;
    float* mu_out = logits + (size_t)T_LEN * VOCAB;            // MU output region

    unsigned short* w2b = (unsigned short*)d_ws;               // w2 bf16 (103 MB)
    unsigned short* hb  = (unsigned short*)((char*)d_ws + (size_t)VOCAB * DIM * 2);
    float* hpre = logits;   // scratch in logits region; fully overwritten by K5

    mu_kernel<<<dim3(T_LEN), dim3(256), 0, stream>>>(ids, tokw, pos, mu_out);
    gemm1_gelu_kernel<<<dim3(T_LEN / 16, DIM / 256), dim3(256), 0, stream>>>(
        mu_out, w1, b1, hpre);
    ln_kernel<<<dim3(T_LEN), dim3(256), 0, stream>>>(hpre, lnw, lnb, hb);
    cvt_kernel<<<dim3(2048), dim3(256), 0, stream>>>(
        w2, (unsigned int*)w2b, (int)((size_t)VOCAB * DIM / 8));
    const int ntiles_n = (VOCAB + 255) / 256;   // 197
    gemm2_kernel<<<dim3(8 * ntiles_n), dim3(512), 0, stream>>>(hb, w2b, b2, logits);
}

// Round 11
// 456.405 us; speedup vs baseline: 1.0101x; 1.0101x over previous
//
#include <hip/hip_runtime.h>
#include <hip/hip_bf16.h>
#include <math.h>

#define T_LEN 2048
#define RC 256
#define DIM 1024
#define VOCAB 50257
#define NT 32               // K tiles: 1024 / 32
#define ASLOT 8192          // A slot: 256 rows x 32 cols ushort = 16 KB
#define BSLOT 4096          // B slot: 128 rows x 32 cols ushort = 8 KB

using short8  = __attribute__((ext_vector_type(8))) short;
using f32x4   = __attribute__((ext_vector_type(4))) float;

#define VMCNT(n) asm volatile("s_waitcnt vmcnt(" #n ")" ::: "memory")
#define LGKM(n)  asm volatile("s_waitcnt lgkmcnt(" #n ")" ::: "memory")
#define SCHED_FENCE() __builtin_amdgcn_sched_barrier(0)

__device__ __forceinline__ unsigned short f2bf(float f) {
    unsigned int u = __float_as_uint(f);
    u += 0x7fffu + ((u >> 16) & 1u);          // round-to-nearest-even
    return (unsigned short)(u >> 16);
}

// HW packed cvt: dst = {lo16=bf16(a), hi16=bf16(b)}, RNE
__device__ __forceinline__ unsigned int cvt_pk_bf16(float a, float b) {
    unsigned int r;
    asm volatile("v_cvt_pk_bf16_f32 %0, %1, %2" : "=v"(r) : "v"(a), "v"(b));
    return r;
}

__device__ __forceinline__ void async_load16(void* lds, const void* g) {
    __builtin_amdgcn_global_load_lds(
        (const __attribute__((address_space(1))) void*)g,
        (__attribute__((address_space(3))) void*)lds,
        16, 0, 0);
}

// ---------------- K1: MU = gather(token_to_mu_w^T, ids) + pos ----------------
__global__ __launch_bounds__(256) void mu_kernel(
    const int* __restrict__ ids, const float* __restrict__ tokw,
    const float* __restrict__ pos, float* __restrict__ mu) {
    int t = blockIdx.x, k = threadIdx.x;
    int id = ids[t];
    float v = tokw[(size_t)k * VOCAB + id] + pos[t * RC + k];
    mu[t * RC + k] = v;
}

// ---------------- K2: h_pre = gelu(MU @ w1^T + b1) ----------------
__global__ __launch_bounds__(256) void gemm1_gelu_kernel(
    const float* __restrict__ mu, const float* __restrict__ w1,
    const float* __restrict__ b1, float* __restrict__ hpre) {
    __shared__ float xs[16][RC];
    const int tg = blockIdx.x, ng = blockIdx.y, tid = threadIdx.x;
    const int t0 = tg * 16;
    {
        const float4* src = (const float4*)(mu + (size_t)t0 * RC);
        float4* dst = (float4*)&xs[0][0];
        #pragma unroll
        for (int i = 0; i < 4; ++i) dst[tid + 256 * i] = src[tid + 256 * i];
    }
    __syncthreads();
    const int d = ng * 256 + tid;
    float acc[16];
    const float bias = b1[d];
    #pragma unroll
    for (int t = 0; t < 16; ++t) acc[t] = bias;
    const float4* w1r = (const float4*)(w1 + (size_t)d * RC);
    for (int k4 = 0; k4 < RC / 4; ++k4) {
        const float4 w = w1r[k4];
        #pragma unroll
        for (int t = 0; t < 16; ++t) {
            const float4 xv = *(const float4*)&xs[t][k4 * 4];
            acc[t] += w.x * xv.x + w.y * xv.y + w.z * xv.z + w.w * xv.w;
        }
    }
    #pragma unroll
    for (int t = 0; t < 16; ++t) {
        float x = acc[t];
        float g = 0.5f * x * (1.0f + erff(x * 0.70710678118654752f));
        hpre[(size_t)(t0 + t) * DIM + d] = g;
    }
}

// ---------------- K3: LayerNorm -> bf16 h ----------------
__global__ __launch_bounds__(256) void ln_kernel(
    const float* __restrict__ hpre, const float* __restrict__ lnw,
    const float* __restrict__ lnb, unsigned short* __restrict__ h) {
    const int t = blockIdx.x, tid = threadIdx.x;
    const float4 v = ((const float4*)(hpre + (size_t)t * DIM))[tid];
    float s  = v.x + v.y + v.z + v.w;
    float ss = v.x * v.x + v.y * v.y + v.z * v.z + v.w * v.w;
    #pragma unroll
    for (int off = 32; off > 0; off >>= 1) {
        s  += __shfl_down(s, off, 64);
        ss += __shfl_down(ss, off, 64);
    }
    __shared__ float red[8];
    const int wid = tid >> 6, lane = tid & 63;
    if (lane == 0) { red[wid] = s; red[4 + wid] = ss; }
    __syncthreads();
    const float S  = red[0] + red[1] + red[2] + red[3];
    const float SS = red[4] + red[5] + red[6] + red[7];
    const float mean = S * (1.0f / DIM);
    const float var  = SS * (1.0f / DIM) - mean * mean;
    const float inv  = 1.0f / sqrtf(var + 1e-6f);
    const float4 wv = ((const float4*)lnw)[tid];
    const float4 bv = ((const float4*)lnb)[tid];
    ushort4 o;
    o.x = f2bf((v.x - mean) * inv * wv.x + bv.x);
    o.y = f2bf((v.y - mean) * inv * wv.y + bv.y);
    o.z = f2bf((v.z - mean) * inv * wv.z + bv.z);
    o.w = f2bf((v.w - mean) * inv * wv.w + bv.w);
    ((ushort4*)h)[(size_t)t * (DIM / 4) + tid] = o;
}

// ---------------- K4: w2 f32 -> bf16 (HW packed cvt) ----------------
__global__ __launch_bounds__(256) void cvt_kernel(
    const float* __restrict__ src, unsigned int* __restrict__ dst, int n8) {
    int i = blockIdx.x * 256 + threadIdx.x;
    const int stride = gridDim.x * 256;
    for (; i < n8; i += stride) {
        const float4 a = ((const float4*)src)[2 * i];
        const float4 b = ((const float4*)src)[2 * i + 1];
        uint4 o;
        o.x = cvt_pk_bf16(a.x, a.y);
        o.y = cvt_pk_bf16(a.z, a.w);
        o.z = cvt_pk_bf16(b.x, b.y);
        o.w = cvt_pk_bf16(b.z, b.w);
        ((uint4*)dst)[i] = o;
    }
}

// ---------------- K5: logits = h @ w2^T + b2 ----------------
// 256x128 block, 256 threads, 4 waves (2M x 2N), wave tile 128x64
// (DS ratio 12 b128 / 32 MFMA = 0.375).  BK=32, ring-3 LDS (72 KiB),
// 2 blocks/CU -> independent-wave overlap (m114).  Stage distance 2,
// derived vmcnt(4); pipelined frag loads w/ counted lgkm; T1/T2/T5.
__device__ __forceinline__ void stage_A256(
    const unsigned short* __restrict__ A, unsigned short* dst,
    int m0, int kt, int tid, int gsrc) {
    #pragma unroll
    for (int p = 0; p < 4; ++p) {
        const int idx = p * 256 + tid;
        const int row = idx >> 2;
        async_load16(dst + (size_t)idx * 8,
                     A + (size_t)(m0 + row) * DIM + kt * 32 + gsrc * 8);
    }
}
__device__ __forceinline__ void stage_B256(
    const unsigned short* __restrict__ B, unsigned short* dst,
    int n0, int kt, int tid, int gsrc) {
    #pragma unroll
    for (int p = 0; p < 2; ++p) {
        const int idx = p * 256 + tid;
        int row = n0 + (idx >> 2); if (row > VOCAB - 1) row = VOCAB - 1;
        async_load16(dst + (size_t)idx * 8,
                     B + (size_t)row * DIM + kt * 32 + gsrc * 8);
    }
}

// One K-tile: 2 phases.  BF_USE = tile t's B frags; BF_LOAD <- tile t+1's.
#define TILE_BODY(T, BF_USE, BF_LOAD)                                          \
  {                                                                            \
    const int t_  = (T);                                                       \
    const int cur = t_ % 3;                                                    \
    const int nxt = (t_ + 1) % 3;                                              \
    const int st  = (t_ + 2) % 3;                                              \
    const unsigned short* As_t = As + cur * ASLOT;                             \
    /* ---- phase even: MFMA af_e x BF_USE ---- */                             \
    _Pragma("unroll")                                                          \
    for (int m = 0; m < 4; ++m)                                                \
        af_o[m] = *(const short8*)(As_t + (arow0 + (m + 4) * 16) * 32 + xr);   \
    if (t_ + 2 < NT)                                                           \
        stage_A256(A, As + st * ASLOT, m0, t_ + 2, tid, gsrc);                 \
    SCHED_FENCE();                                                             \
    LGKM(4);              /* af_e + BF_USE landed; af_o may fly */             \
    SCHED_FENCE();                                                             \
    __builtin_amdgcn_s_setprio(1);                                             \
    _Pragma("unroll")                                                          \
    for (int m = 0; m < 4; ++m)                                                \
        _Pragma("unroll")                                                      \
        for (int n = 0; n < 4; ++n)                                            \
            acc[m][n] = __builtin_amdgcn_mfma_f32_16x16x32_bf16(               \
                af_e[m], BF_USE[n], acc[m][n], 0, 0, 0);                       \
    __builtin_amdgcn_s_setprio(0);                                             \
    SCHED_FENCE();                                                             \
    if (t_ < NT - 2) { VMCNT(4); } else { VMCNT(0); }                          \
    __builtin_amdgcn_s_barrier();   /* tile t+1 LDS ready for all waves */     \
    /* ---- phase odd: MFMA af_o x BF_USE ---- */                              \
    if (t_ + 1 < NT) {                                                         \
        const unsigned short* As_n = As + nxt * ASLOT;                         \
        const unsigned short* Bs_n = Bs + nxt * BSLOT;                         \
        _Pragma("unroll")                                                      \
        for (int m = 0; m < 4; ++m)                                            \
            af_e[m] = *(const short8*)(As_n + (arow0 + m * 16) * 32 + xr);     \
        _Pragma("unroll")                                                      \
        for (int n = 0; n < 4; ++n)                                            \
            BF_LOAD[n] = *(const short8*)(Bs_n + (brow0 + n * 16) * 32 + xr);  \
    }                                                                          \
    if (t_ + 2 < NT)                                                           \
        stage_B256(B, Bs + st * BSLOT, n0, t_ + 2, tid, gsrc);                 \
    SCHED_FENCE();                                                             \
    if (t_ + 1 < NT) { LGKM(8); } else { LGKM(0); }  /* af_o landed */         \
    SCHED_FENCE();                                                             \
    __builtin_amdgcn_s_setprio(1);                                             \
    _Pragma("unroll")                                                          \
    for (int m = 0; m < 4; ++m)                                                \
        _Pragma("unroll")                                                      \
        for (int n = 0; n < 4; ++n)                                            \
            acc[m + 4][n] = __builtin_amdgcn_mfma_f32_16x16x32_bf16(           \
                af_o[m], BF_USE[n], acc[m + 4][n], 0, 0, 0);                   \
    __builtin_amdgcn_s_setprio(0);                                             \
    SCHED_FENCE();                                                             \
    __builtin_amdgcn_s_barrier();   /* reads done before next stage reuses */  \
  }

__global__ __launch_bounds__(256, 2) void gemm2_kernel(
    const unsigned short* __restrict__ A, const unsigned short* __restrict__ B,
    const float* __restrict__ b2, float* __restrict__ out) {
    __shared__ unsigned short As[3 * ASLOT];   // 48 KiB
    __shared__ unsigned short Bs[3 * BSLOT];   // 24 KiB

    const int tid  = threadIdx.x;
    // T1: bijective XCD swizzle (gridDim.x = 3144 = 8*393), M-fastest
    const int cpx  = gridDim.x >> 3;   // 393
    const int wgid = (blockIdx.x & 7) * cpx + (blockIdx.x >> 3);
    const int m0   = (wgid & 7) << 8;    // 8 M-tiles of 256
    const int n0   = (wgid >> 3) << 7;   // 393 N-tiles of 128

    const int lane = tid & 63;
    const int lr   = lane & 15;
    const int lk   = lane >> 4;
    const int wid  = tid >> 6;
    const int wr   = wid >> 1;          // 0..1  (M)
    const int wc   = wid & 1;           // 0..1  (N)
    // T2 read-side swizzle (conflict-free, verified R2-R10)
    const int xr   = (lk ^ ((lr >> 1) & 3)) * 8;   // ushort offset within row
    const int arow0 = wr * 128 + lr;
    const int brow0 = wc * 64 + lr;
    // T2 source-side granule for linear global_load_lds dest
    const int gsrc = (tid & 3) ^ ((tid >> 3) & 3);

    f32x4 acc[8][4];
    #pragma unroll
    for (int m = 0; m < 8; ++m)
        #pragma unroll
        for (int n = 0; n < 4; ++n) acc[m][n] = {0.f, 0.f, 0.f, 0.f};

    // prologue: stage tiles 0,1 (issue order fenced -> vmcnt exact)
    stage_A256(A, As, m0, 0, tid, gsrc);
    stage_B256(B, Bs, n0, 0, tid, gsrc);
    SCHED_FENCE();
    stage_A256(A, As + ASLOT, m0, 1, tid, gsrc);
    stage_B256(B, Bs + BSLOT, n0, 1, tid, gsrc);
    SCHED_FENCE();
    VMCNT(6);                       // tile 0 landed; tile 1 (6 ops) in flight
    __builtin_amdgcn_s_barrier();

    // preload tile-0 frags: af_e + bfA
    short8 af_e[4], af_o[4], bfA[4], bfB[4];
    #pragma unroll
    for (int m = 0; m < 4; ++m)
        af_e[m] = *(const short8*)(As + (arow0 + m * 16) * 32 + xr);
    #pragma unroll
    for (int n = 0; n < 4; ++n)
        bfA[n] = *(const short8*)(Bs + (brow0 + n * 16) * 32 + xr);

    #pragma unroll 1
    for (int tt = 0; tt < NT; tt += 2) {
        TILE_BODY(tt,     bfA, bfB);   // uses bfA(tile tt),   loads bfB(tile tt+1)
        TILE_BODY(tt + 1, bfB, bfA);   // uses bfB(tile tt+1), loads bfA(tile tt+2)
    }

    // epilogue: C row = frag_row + (lane>>4)*4 + j, col = lane&15
    float bias[4]; int col[4]; bool ok[4];
    #pragma unroll
    for (int n = 0; n < 4; ++n) {
        col[n] = n0 + wc * 64 + n * 16 + lr;
        ok[n]  = col[n] < VOCAB;
        bias[n] = ok[n] ? b2[col[n]] : 0.f;
    }
    #pragma unroll
    for (int m = 0; m < 8; ++m) {
        const int row = m0 + wr * 128 + m * 16 + lk * 4;
        #pragma unroll
        for (int n = 0; n < 4; ++n) {
            if (ok[n]) {
                #pragma unroll
                for (int j = 0; j < 4; ++j)
                    out[(size_t)(row + j) * VOCAB + col[n]] = acc[m][n][j] + bias[n];
            }
        }
    }
}

extern "C" void kernel_launch(void* const* d_in, const int* in_sizes, int n_in,
                              void* d_out, int out_size, void* d_ws, size_t ws_size,
                              hipStream_t stream) {
    (void)in_sizes; (void)n_in; (void)out_size; (void)ws_size;
    const int*   ids  = (const int*)d_in[0];
    const float* tokw = (const float*)d_in[1];
    const float* pos  = (const float*)d_in[2];
    const float* w1   = (const float*)d_in[3];
    const float* b1   = (const float*)d_in[4];
    const float* lnw  = (const float*)d_in[5];
    const float* lnb  = (const float*)d_in[6];
    const float* w2   = (const float*)d_in[7];
    const float* b2   = (const float*)d_in[8];

    float* logits = (float*)d_out;
    float* mu_out = logits + (size_t)T_LEN * VOCAB;            // MU output region

    unsigned short* w2b = (unsigned short*)d_ws;               // w2 bf16 (103 MB)
    unsigned short* hb  = (unsigned short*)((char*)d_ws + (size_t)VOCAB * DIM * 2);
    float* hpre = logits;   // scratch in logits region; fully overwritten by K5

    mu_kernel<<<dim3(T_LEN), dim3(256), 0, stream>>>(ids, tokw, pos, mu_out);
    gemm1_gelu_kernel<<<dim3(T_LEN / 16, DIM / 256), dim3(256), 0, stream>>>(
        mu_out, w1, b1, hpre);
    ln_kernel<<<dim3(T_LEN), dim3(256), 0, stream>>>(hpre, lnw, lnb, hb);
    cvt_kernel<<<dim3(2048), dim3(256), 0, stream>>>(
        w2, (unsigned int*)w2b, (int)((size_t)VOCAB * DIM / 8));
    const int ntiles_n = (VOCAB + 127) / 128;   // 393
    gemm2_kernel<<<dim3(8 * ntiles_n), dim3(256), 0, stream>>>(hb, w2b, b2, logits);
}